// Round 1
// baseline (104.109 us; speedup 1.0000x reference)
//
#include <hip/hip_runtime.h>

// Problem constants (fixed shapes from setup_inputs)
constexpr int N  = 4, C = 64, H = 16, W = 16;
constexpr int NF = 128;                 // filters
constexpr int OH = 16, OW = 16;
constexpr int D  = C * 9;               // 576 = C*FH*FW
constexpr int P  = N * OH * OW;         // 1024 patches
constexpr float EPSF = 1e-5f;

// ---------------------------------------------------------------------------
// K1: unfold x -> x_col (P x D, row-major) and transpose w -> w_t (D x NF)
// ---------------------------------------------------------------------------
__global__ void k_prep(const float* __restrict__ x, const float* __restrict__ w,
                       float* __restrict__ x_col, float* __restrict__ w_t) {
    int gid = blockIdx.x * blockDim.x + threadIdx.x;
    if (gid < P * D) {
        int p = gid / D, d = gid % D;
        int n = p / (OH * OW), rem = p % (OH * OW);
        int oh = rem / OW, ow = rem % OW;
        int c = d / 9, k = d % 9;
        int fh = k / 3, fw = k % 3;
        int ih = oh + fh - 1, iw = ow + fw - 1;   // pad = 1
        float v = 0.0f;
        if (ih >= 0 && ih < H && iw >= 0 && iw < W)
            v = x[((n * C + c) * H + ih) * W + iw];
        x_col[gid] = v;
    } else {
        int g = gid - P * D;
        if (g < D * NF) {
            int k = g / NF, f = g % NF;           // w_t[k][f] = w[f][k]
            w_t[g] = w[f * D + k];
        }
    }
}

// ---------------------------------------------------------------------------
// K2: s[p,f] = dot(x_col[p,:], w[f,:]) in fp64 ; t[p,f] = 2*r[p,f]/(2*s+eps)
// One block per patch, 128 threads (thread = filter).
// x_col[p,k] is block-uniform -> scalar loads; w_t[k][f] coalesced over lanes.
// ---------------------------------------------------------------------------
__global__ void __launch_bounds__(NF) k_s_t(
        const float* __restrict__ x_col, const float* __restrict__ w_t,
        const float* __restrict__ r, float* __restrict__ t_out) {
    const int p = blockIdx.x;
    const int f = threadIdx.x;            // 0..127
    const float* __restrict__ xr = x_col + p * D;
    const float* __restrict__ wt = w_t + f;
    double acc = 0.0;
#pragma unroll 8
    for (int k = 0; k < D; ++k) {
        acc += (double)xr[k] * (double)wt[k * NF];
    }
    const int n = p / (OH * OW), rem = p % (OH * OW);
    const float rv = r[(n * NF + f) * (OH * OW) + rem];   // r_col[p,f]
    const double denom = 2.0 * acc + (double)EPSF;
    t_out[p * NF + f] = (float)((2.0 * (double)rv) / denom);
}

// ---------------------------------------------------------------------------
// K3: r_new[p,d] = x_col[p,d] * sum_f w[f,d] * t[p,f]
// One block per patch, 576 threads (thread = d). t[p,f] block-uniform.
// ---------------------------------------------------------------------------
__global__ void __launch_bounds__(D) k_g(
        const float* __restrict__ x_col, const float* __restrict__ w,
        const float* __restrict__ t_in, float* __restrict__ r_new) {
    const int p = blockIdx.x;
    const int d = threadIdx.x;            // 0..575
    const float* __restrict__ tp = t_in + p * NF;
    float acc = 0.0f;
#pragma unroll 8
    for (int f = 0; f < NF; ++f) {
        acc += tp[f] * w[f * D + d];
    }
    r_new[p * D + d] = x_col[p * D + d] * acc;
}

// ---------------------------------------------------------------------------
// K4: fold (adjoint of unfold): out[n,c,h,w] = sum over valid (fh,fw) of
//     r_new[p(n, h+1-fh, w+1-fw), c*9 + fh*3 + fw]
// ---------------------------------------------------------------------------
__global__ void k_fold(const float* __restrict__ r_new, float* __restrict__ out) {
    int gid = blockIdx.x * blockDim.x + threadIdx.x;  // (n,c,h,w), w fastest
    if (gid >= N * C * H * W) return;
    int w_ = gid % W;
    int h  = (gid / W) % H;
    int c  = (gid / (W * H)) % C;
    int n  = gid / (W * H * C);
    float acc = 0.0f;
#pragma unroll
    for (int fh = 0; fh < 3; ++fh) {
        int oh = h + 1 - fh;
        if (oh < 0 || oh >= OH) continue;
#pragma unroll
        for (int fw = 0; fw < 3; ++fw) {
            int ow = w_ + 1 - fw;
            if (ow < 0 || ow >= OW) continue;
            int p = (n * OH + oh) * OW + ow;
            acc += r_new[p * D + c * 9 + fh * 3 + fw];
        }
    }
    out[gid] = acc;
}

// ---------------------------------------------------------------------------
extern "C" void kernel_launch(void* const* d_in, const int* in_sizes, int n_in,
                              void* d_out, int out_size, void* d_ws, size_t ws_size,
                              hipStream_t stream) {
    const float* x = (const float*)d_in[0];   // (4,64,16,16)
    const float* r = (const float*)d_in[1];   // (4,128,16,16)
    const float* w = (const float*)d_in[2];   // (128,64,3,3) -> (128,576)
    float* out = (float*)d_out;               // (4,64,16,16)

    // workspace layout (floats): x_col | w_t | t | r_new   (~5.3 MB total)
    float* ws    = (float*)d_ws;
    float* x_col = ws;                        // P*D   = 589824
    float* w_t   = x_col + P * D;             // D*NF  =  73728
    float* t     = w_t + D * NF;              // P*NF  = 131072
    float* r_new = t + P * NF;                // P*D   = 589824

    {
        int total = P * D + D * NF;
        k_prep<<<(total + 255) / 256, 256, 0, stream>>>(x, w, x_col, w_t);
    }
    k_s_t<<<P, NF, 0, stream>>>(x_col, w_t, r, t);
    k_g<<<P, D, 0, stream>>>(x_col, w, t, r_new);
    {
        int total = N * C * H * W;
        k_fold<<<(total + 255) / 256, 256, 0, stream>>>(r_new, out);
    }
}